// Round 11
// baseline (225.844 us; speedup 1.0000x reference)
//
#include <hip/hip_runtime.h>
#include <cstdint>

// ---------------- problem constants ----------------
#define E_    8
#define H_    1024
#define F_    2048          // per-half FFN width (W1 has 2F cols)
#define NTOK  4096
#define CAP   1280          // int(1.25 * (4096*2/8))
#define ECAP  (E_*CAP)      // 10240 buffer rows

typedef unsigned short u16;
typedef __attribute__((ext_vector_type(8))) short bf16x8;   // 8 bf16 = 4 VGPRs
typedef __attribute__((ext_vector_type(4))) float f32x4;
typedef __attribute__((ext_vector_type(4))) unsigned short u16x4;

// ---------------- helpers ----------------
__device__ __forceinline__ u16 f2bf(float f) {      // RNE float->bf16
  union { float f; uint32_t u; } v; v.f = f;
  uint32_t r = v.u + 0x7fffu + ((v.u >> 16) & 1u);
  return (u16)(r >> 16);
}

// async global->LDS, 16B per lane; LDS dest = wave-uniform base + lane*16
__device__ __forceinline__ void gld16(const void* gsrc, void* ldst) {
  auto g = reinterpret_cast<const __attribute__((address_space(1))) uint32_t*>(
      reinterpret_cast<uintptr_t>(gsrc));
  auto l = reinterpret_cast<__attribute__((address_space(3))) uint32_t*>(
      reinterpret_cast<uintptr_t>(ldst));
  __builtin_amdgcn_global_load_lds(g, l, 16, 0, 0);
}

// XOR bank swizzle for [rows][64] bf16 LDS tiles: byte ^= ((row&7)<<4)
__device__ __forceinline__ int swz(int row, int chunk) {
  return row * 64 + ((chunk ^ (row & 7)) * 8);
}

// ---------------- K-A: fused {W1 transpose+cvt} + router ----------------
// blocks 0..8191: W1 tiles; 8192..9215: router (4 tokens each)
__global__ __launch_bounds__(256) void prep_kernel(const float* __restrict__ W1,
                                                   u16* __restrict__ W1T,
                                                   const float* __restrict__ x,
                                                   const float* __restrict__ Wr,
                                                   int* __restrict__ e0o, int* __restrict__ e1o,
                                                   float* __restrict__ v0o, float* __restrict__ v1o,
                                                   float* __restrict__ partial) {
  int b = blockIdx.x;
  if (b < 8192) {
    // ------- W1 transpose + fp32->bf16 (64x64 tile, fp32 LDS [64][65]) -------
    __shared__ float tile[64][65];
    int slab = b >> 10, t = b & 1023;
    int rt = t >> 6, ct = t & 63;             // 16 x 64 tiles
    const int R = H_, C = 2 * F_;
    const float* in = W1 + (size_t)slab * R * C;
    u16* outp = W1T + (size_t)slab * R * C;
    int r0 = rt * 64, c0 = ct * 64;
    int tx = threadIdx.x & 15, ty = threadIdx.x >> 4;
#pragma unroll
    for (int i = 0; i < 4; i++) {
      int row = ty + 16 * i;
      float4 v = *(const float4*)(in + (size_t)(r0 + row) * C + c0 + tx * 4);
      tile[row][tx * 4 + 0] = v.x;
      tile[row][tx * 4 + 1] = v.y;
      tile[row][tx * 4 + 2] = v.z;
      tile[row][tx * 4 + 3] = v.w;
    }
    __syncthreads();
#pragma unroll
    for (int i = 0; i < 4; i++) {
      int c = ty + 16 * i;
      u16x4 bq;
      bq.x = f2bf(tile[tx * 4 + 0][c]);
      bq.y = f2bf(tile[tx * 4 + 1][c]);
      bq.z = f2bf(tile[tx * 4 + 2][c]);
      bq.w = f2bf(tile[tx * 4 + 3][c]);
      *(u16x4*)(outp + (size_t)(c0 + c) * R + r0 + tx * 4) = bq;
    }
  } else {
    // ------- router: 4 tokens per block (one wave each) -------
    int blk = b - 8192;
    int w = threadIdx.x >> 6, l = threadIdx.x & 63;
    int t = blk * 4 + w;
    const float* xr = x + (size_t)t * H_;
    float acc[8] = {0.f,0.f,0.f,0.f,0.f,0.f,0.f,0.f};
#pragma unroll
    for (int it = 0; it < 16; ++it) {
      int h = it * 64 + l;
      float xv = xr[h];
      const float4* wr = (const float4*)(Wr + h * 8);
      float4 wa = wr[0], wb = wr[1];
      acc[0] += xv * wa.x; acc[1] += xv * wa.y; acc[2] += xv * wa.z; acc[3] += xv * wa.w;
      acc[4] += xv * wb.x; acc[5] += xv * wb.y; acc[6] += xv * wb.z; acc[7] += xv * wb.w;
    }
#pragma unroll
    for (int e = 0; e < 8; ++e)
#pragma unroll
      for (int off = 32; off; off >>= 1)
        acc[e] += __shfl_xor(acc[e], off);

    __shared__ float pg[4][8];
    if (l == 0) {
      float mx = acc[0];
#pragma unroll
      for (int e = 1; e < 8; ++e) mx = fmaxf(mx, acc[e]);
      float g[8], s = 0.f;
#pragma unroll
      for (int e = 0; e < 8; ++e) { g[e] = __expf(acc[e] - mx); s += g[e]; }
      float inv = 1.f / s;
#pragma unroll
      for (int e = 0; e < 8; ++e) g[e] *= inv;
      int b0 = 0; float m0 = g[0];
#pragma unroll
      for (int e = 1; e < 8; ++e) if (g[e] > m0) { m0 = g[e]; b0 = e; }
      int b1 = -1; float m1 = -1.f;
#pragma unroll
      for (int e = 0; e < 8; ++e) if (e != b0 && g[e] > m1) { m1 = g[e]; b1 = e; }
      e0o[t] = b0; e1o[t] = b1; v0o[t] = m0; v1o[t] = m1;
#pragma unroll
      for (int e = 0; e < 8; ++e) pg[w][e] = g[e];
    }
    __syncthreads();
    if (threadIdx.x < 8) {
      int e = threadIdx.x;
      partial[blk * 8 + e] = pg[0][e] + pg[1][e] + pg[2][e] + pg[3][e];
    }
  }
}

// ---------------- K-C: capacity scan (+ per-expert used-row counts) ----------------
__global__ __launch_bounds__(256) void scan_kernel(const int* __restrict__ e0i, const int* __restrict__ e1i,
                                                   const float* __restrict__ partial,
                                                   int* __restrict__ slot0, int* __restrict__ slot1,
                                                   int* __restrict__ used_out,
                                                   float* __restrict__ bl_out) {
  __shared__ int c0[256][8], c1[256][8];
  __shared__ float gs[256][8];
  __shared__ int used0_s[8], tot1_s[8];
  int tid = threadIdx.x;

  int le0[16], le1[16];
  int lc0[8] = {0,0,0,0,0,0,0,0}, lc1[8] = {0,0,0,0,0,0,0,0};
  for (int i = 0; i < 16; ++i) {
    int t = tid * 16 + i;
    le0[i] = e0i[t]; le1[i] = e1i[t];
    lc0[le0[i]]++; lc1[le1[i]]++;
  }
#pragma unroll
  for (int e = 0; e < 8; ++e) { c0[tid][e] = lc0[e]; c1[tid][e] = lc1[e]; }

  float g[8] = {0.f,0.f,0.f,0.f,0.f,0.f,0.f,0.f};
  for (int rr = 0; rr < 4; ++rr)
#pragma unroll
    for (int e = 0; e < 8; ++e) g[e] += partial[(tid + rr * 256) * 8 + e];
#pragma unroll
  for (int e = 0; e < 8; ++e) gs[tid][e] = g[e];
  __syncthreads();

  for (int d = 1; d < 256; d <<= 1) {
    int t0[8], t1[8];
    bool a = (tid >= d);
    if (a) {
#pragma unroll
      for (int e = 0; e < 8; ++e) { t0[e] = c0[tid - d][e]; t1[e] = c1[tid - d][e]; }
    }
    __syncthreads();
    if (a) {
#pragma unroll
      for (int e = 0; e < 8; ++e) { c0[tid][e] += t0[e]; c1[tid][e] += t1[e]; }
    }
    __syncthreads();
  }
  for (int s = 128; s > 0; s >>= 1) {
    if (tid < s)
#pragma unroll
      for (int e = 0; e < 8; ++e) gs[tid][e] += gs[tid + s][e];
    __syncthreads();
  }
  if (tid < 8) {
    int e = tid;
    int u0 = min(c0[255][e], CAP);
    int t1 = c1[255][e];
    used0_s[e] = u0;
    tot1_s[e] = t1;
    used_out[e] = u0 + min(t1, max(0, CAP - u0));
  }
  __syncthreads();

  int ex0[8], ex1[8];
#pragma unroll
  for (int e = 0; e < 8; ++e) { ex0[e] = c0[tid][e] - lc0[e]; ex1[e] = c1[tid][e] - lc1[e]; }
  int r0c[8] = {0,0,0,0,0,0,0,0}, r1c[8] = {0,0,0,0,0,0,0,0};
  for (int i = 0; i < 16; ++i) {
    int t = tid * 16 + i;
    int e = le0[i];
    int pos = ex0[e] + r0c[e]; r0c[e]++;
    slot0[t] = (pos < CAP) ? (e * CAP + pos) : -1;
    e = le1[i];
    pos = ex1[e] + r1c[e] + used0_s[e]; r1c[e]++;
    slot1[t] = (pos < CAP) ? (e * CAP + pos) : -1;
  }

  if (tid == 0) {
    float bl = 0.f;
    for (int e = 0; e < 8; ++e) {
      int u1 = min(tot1_s[e], max(0, CAP - used0_s[e]));
      float used = (float)(used0_s[e] + u1);
      float fu = fmaxf(used, 1e-9f) / (8192.f + 1e-9f);
      bl += (gs[0][e] / (float)NTOK) * fu;
    }
    bl_out[0] = bl * 8.f;
  }
}

// ---------------- K-D: scatter tokens into expert buffer (bf16) ----------------
__global__ __launch_bounds__(256) void scatter_kernel(const float* __restrict__ x,
                                                      const int* __restrict__ slot0,
                                                      const int* __restrict__ slot1,
                                                      u16* __restrict__ xe) {
  int t = blockIdx.x, tid = threadIdx.x;
  float4 vv = *(const float4*)(x + (size_t)t * H_ + tid * 4);
  u16x4 b;
  b.x = f2bf(vv.x); b.y = f2bf(vv.y); b.z = f2bf(vv.z); b.w = f2bf(vv.w);
  int s0 = slot0[t], s1 = slot1[t];
  if (s0 >= 0) *(u16x4*)(xe + (size_t)s0 * H_ + tid * 4) = b;
  if (s1 >= 0) *(u16x4*)(xe + (size_t)s1 * H_ + tid * 4) = b;
}

// ---------------- K-E: fused {GEMM1 + SwiGLU} + {W2 transpose+cvt} ----------------
// 6656 blocks in groups of 13: 5 gemm1 tiles + 8 W2-transpose tiles (interleaved for co-residency).
// Union LDS: gemm1 needs exactly 32KB; transpose needs 16.6KB of the same buffer.
__global__ __launch_bounds__(256) void ffn1_kernel(const u16* __restrict__ xe,
                                                   const u16* __restrict__ W1T,
                                                   const int* __restrict__ used_tot,
                                                   u16* __restrict__ act,
                                                   const float* __restrict__ W2,
                                                   u16* __restrict__ W2T) {
  __shared__ char lds[32768];
  const int g = blockIdx.x / 13, r = blockIdx.x % 13;

  if (r < 5) {
    // ---------------- gemm1 tile (id 0..2559) ----------------
    const int id = g * 5 + r;
    const int bx = id & 31;                   // f-tile
    const int by = id >> 5;                   // m-tile
    const int mbase = by * 128;
    const int e = mbase / 1280;
    if (mbase - e * 1280 >= used_tot[e]) return;

    u16* As  = (u16*)lds;                     // 128*64*2 = 16384
    u16* Bsa = (u16*)(lds + 16384);           // 64*64*2  =  8192
    u16* Bsb = (u16*)(lds + 24576);           //             8192
    const int tid = threadIdx.x;
    const int w = tid >> 6, l = tid & 63;
    const int wm = w & 1, wn = w >> 1;
    const int nbase = bx * 64;
    const u16* Ap = xe + (size_t)mbase * H_;
    const u16* Ba = W1T + (size_t)e * 4096 * H_ + (size_t)nbase * H_;
    const u16* Bb = Ba + (size_t)F_ * H_;
    const int lrow = l >> 3;
    const int lcol = (((l & 7) ^ lrow) * 8);  // pre-swizzled global chunk

    f32x4 acca[4][2] = {};
    f32x4 accb[4][2] = {};

    for (int kt = 0; kt < 16; ++kt) {
      int k0 = kt * 64;
#pragma unroll
      for (int rr = 0; rr < 4; ++rr) {
        int row0 = w * 32 + rr * 8;
        gld16(Ap + (size_t)(row0 + lrow) * H_ + k0 + lcol, &As[row0 * 64]);
      }
#pragma unroll
      for (int rr = 0; rr < 2; ++rr) {
        int row0 = w * 16 + rr * 8;
        gld16(Ba + (size_t)(row0 + lrow) * H_ + k0 + lcol, &Bsa[row0 * 64]);
        gld16(Bb + (size_t)(row0 + lrow) * H_ + k0 + lcol, &Bsb[row0 * 64]);
      }
      __syncthreads();
#pragma unroll
      for (int kk = 0; kk < 64; kk += 32) {
        const int ck = (kk >> 3) + (l >> 4);
        bf16x8 af[4], ba[2], bb[2];
#pragma unroll
        for (int i = 0; i < 4; ++i)
          af[i] = *(const bf16x8*)&As[swz(wm * 64 + i * 16 + (l & 15), ck)];
#pragma unroll
        for (int j = 0; j < 2; ++j) {
          ba[j] = *(const bf16x8*)&Bsa[swz(wn * 32 + j * 16 + (l & 15), ck)];
          bb[j] = *(const bf16x8*)&Bsb[swz(wn * 32 + j * 16 + (l & 15), ck)];
        }
#pragma unroll
        for (int i = 0; i < 4; ++i)
#pragma unroll
          for (int j = 0; j < 2; ++j) {
            acca[i][j] = __builtin_amdgcn_mfma_f32_16x16x32_bf16(af[i], ba[j], acca[i][j], 0, 0, 0);
            accb[i][j] = __builtin_amdgcn_mfma_f32_16x16x32_bf16(af[i], bb[j], accb[i][j], 0, 0, 0);
          }
      }
      __syncthreads();
    }
#pragma unroll
    for (int i = 0; i < 4; ++i)
#pragma unroll
      for (int j = 0; j < 2; ++j)
#pragma unroll
        for (int rr = 0; rr < 4; ++rr) {
          int m = mbase + wm * 64 + i * 16 + (l >> 4) * 4 + rr;
          int f = nbase + wn * 32 + j * 16 + (l & 15);
          float a = acca[i][j][rr];
          float b = accb[i][j][rr];
          float s = a / (1.f + __expf(-a));
          act[(size_t)m * F_ + f] = f2bf(s * b);
        }
  } else {
    // ---------------- W2 transpose tile (id 0..4095) ----------------
    const int id = g * 8 + (r - 5);
    float (*tile)[65] = reinterpret_cast<float(*)[65]>(lds);
    int slab = id >> 9, t = id & 511;
    int rt = t >> 4, ct = t & 15;             // 32 x 16 tiles
    const int R = F_, C = H_;
    const float* in = W2 + (size_t)slab * R * C;
    u16* outp = W2T + (size_t)slab * R * C;
    int r0 = rt * 64, c0 = ct * 64;
    int tx = threadIdx.x & 15, ty = threadIdx.x >> 4;
#pragma unroll
    for (int i = 0; i < 4; i++) {
      int row = ty + 16 * i;
      float4 v = *(const float4*)(in + (size_t)(r0 + row) * C + c0 + tx * 4);
      tile[row][tx * 4 + 0] = v.x;
      tile[row][tx * 4 + 1] = v.y;
      tile[row][tx * 4 + 2] = v.z;
      tile[row][tx * 4 + 3] = v.w;
    }
    __syncthreads();
#pragma unroll
    for (int i = 0; i < 4; i++) {
      int c = ty + 16 * i;
      u16x4 bq;
      bq.x = f2bf(tile[tx * 4 + 0][c]);
      bq.y = f2bf(tile[tx * 4 + 1][c]);
      bq.z = f2bf(tile[tx * 4 + 2][c]);
      bq.w = f2bf(tile[tx * 4 + 3][c]);
      *(u16x4*)(outp + (size_t)(c0 + c) * R + r0 + tx * 4) = bq;
    }
  }
}

// ---------------- K-F: GEMM2 (128x128, XOR-swizzled LDS, early-exit) ----------------
__global__ __launch_bounds__(256, 2) void gemm2_kernel(const u16* __restrict__ act,
                                                       const u16* __restrict__ W2T,
                                                       const int* __restrict__ used_tot,
                                                       float* __restrict__ outb) {
  const int mbase = blockIdx.y * 128;
  const int e = mbase / 1280;
  if (mbase - e * 1280 >= used_tot[e]) return;

  __shared__ u16 As[128 * 64];
  __shared__ u16 Bs[128 * 64];
  const int tid = threadIdx.x;
  const int w = tid >> 6, l = tid & 63;
  const int wm = w & 1, wn = w >> 1;
  const int nbase = blockIdx.x * 128;
  const u16* Ap = act + (size_t)mbase * F_;
  const u16* Bp = W2T + (size_t)e * H_ * F_ + (size_t)nbase * F_;
  const int lrow = l >> 3;
  const int lcol = (((l & 7) ^ lrow) * 8);

  f32x4 acc[4][4] = {};

  for (int kt = 0; kt < 32; ++kt) {
    int k0 = kt * 64;
#pragma unroll
    for (int r = 0; r < 4; ++r) {
      int row0 = w * 32 + r * 8;
      gld16(Ap + (size_t)(row0 + lrow) * F_ + k0 + lcol, &As[row0 * 64]);
      gld16(Bp + (size_t)(row0 + lrow) * F_ + k0 + lcol, &Bs[row0 * 64]);
    }
    __syncthreads();
#pragma unroll
    for (int kk = 0; kk < 64; kk += 32) {
      const int ck = (kk >> 3) + (l >> 4);
      bf16x8 af[4], bf[4];
#pragma unroll
      for (int i = 0; i < 4; ++i)
        af[i] = *(const bf16x8*)&As[swz(wm * 64 + i * 16 + (l & 15), ck)];
#pragma unroll
      for (int j = 0; j < 4; ++j)
        bf[j] = *(const bf16x8*)&Bs[swz(wn * 64 + j * 16 + (l & 15), ck)];
#pragma unroll
      for (int i = 0; i < 4; ++i)
#pragma unroll
        for (int j = 0; j < 4; ++j)
          acc[i][j] = __builtin_amdgcn_mfma_f32_16x16x32_bf16(af[i], bf[j], acc[i][j], 0, 0, 0);
    }
    __syncthreads();
  }
#pragma unroll
  for (int i = 0; i < 4; ++i)
#pragma unroll
    for (int j = 0; j < 4; ++j)
#pragma unroll
      for (int r = 0; r < 4; ++r) {
        int m = mbase + wm * 64 + i * 16 + (l >> 4) * 4 + r;
        int n = nbase + wn * 64 + j * 16 + (l & 15);
        outb[(size_t)m * H_ + n] = acc[i][j][r];
      }
}

// ---------------- K-G: gather + weighted combine ----------------
__global__ __launch_bounds__(256) void combine_kernel(const float* __restrict__ outb,
                                                      const int* __restrict__ slot0,
                                                      const int* __restrict__ slot1,
                                                      const float* __restrict__ v0,
                                                      const float* __restrict__ v1,
                                                      float* __restrict__ y) {
  int t = blockIdx.x, tid = threadIdx.x;
  int s0 = slot0[t], s1 = slot1[t];
  float w0 = v0[t], w1 = v1[t];
  float4 r; r.x = 0.f; r.y = 0.f; r.z = 0.f; r.w = 0.f;
  if (s0 >= 0) {
    float4 a = *(const float4*)(outb + (size_t)s0 * H_ + tid * 4);
    r.x += w0 * a.x; r.y += w0 * a.y; r.z += w0 * a.z; r.w += w0 * a.w;
  }
  if (s1 >= 0) {
    float4 a = *(const float4*)(outb + (size_t)s1 * H_ + tid * 4);
    r.x += w1 * a.x; r.y += w1 * a.y; r.z += w1 * a.z; r.w += w1 * a.w;
  }
  *(float4*)(y + (size_t)t * H_ + tid * 4) = r;
}

// ---------------- workspace layout (bytes) ----------------
#define OFF_W1T   ((size_t)0)           // 8*4096*1024*2  = 64 MiB
#define OFF_W2T   ((size_t)67108864)    // 8*1024*2048*2  = 32 MiB
#define OFF_XE    ((size_t)100663296)   // 10240*1024*2   = 20 MiB
#define OFF_ACT   ((size_t)121634816)   // 10240*2048*2   = 40 MiB
#define OFF_OUTB  ((size_t)163577856)   // 10240*1024*4   = 40 MiB
#define OFF_SLOT0 ((size_t)205520896)
#define OFF_SLOT1 ((size_t)205537280)
#define OFF_V0    ((size_t)205553664)
#define OFF_V1    ((size_t)205570048)
#define OFF_E0    ((size_t)205586432)
#define OFF_E1    ((size_t)205602816)
#define OFF_PART  ((size_t)205619200)   // 1024*8*4
#define OFF_USED  ((size_t)205651968)   // 8*4

extern "C" void kernel_launch(void* const* d_in, const int* in_sizes, int n_in,
                              void* d_out, int out_size, void* d_ws, size_t ws_size,
                              hipStream_t stream) {
  const float* x  = (const float*)d_in[0];
  const float* Wr = (const float*)d_in[1];
  const float* W1 = (const float*)d_in[2];
  const float* W2 = (const float*)d_in[3];
  float* out = (float*)d_out;

  uint8_t* ws = (uint8_t*)d_ws;
  u16*   W1T   = (u16*)(ws + OFF_W1T);
  u16*   W2T   = (u16*)(ws + OFF_W2T);
  u16*   xe    = (u16*)(ws + OFF_XE);
  u16*   act   = (u16*)(ws + OFF_ACT);
  float* outb  = (float*)(ws + OFF_OUTB);
  int*   slot0 = (int*)(ws + OFF_SLOT0);
  int*   slot1 = (int*)(ws + OFF_SLOT1);
  float* v0    = (float*)(ws + OFF_V0);
  float* v1    = (float*)(ws + OFF_V1);
  int*   e0    = (int*)(ws + OFF_E0);
  int*   e1    = (int*)(ws + OFF_E1);
  float* part  = (float*)(ws + OFF_PART);
  int*   used  = (int*)(ws + OFF_USED);

  // W1 transpose/convert + router (W2 deferred into ffn1)
  prep_kernel<<<9216, 256, 0, stream>>>(W1, W1T, x, Wr, e0, e1, v0, v1, part);

  scan_kernel<<<1, 256, 0, stream>>>(e0, e1, part, slot0, slot1, used, out + (size_t)NTOK * H_);
  scatter_kernel<<<NTOK, 256, 0, stream>>>(x, slot0, slot1, xe);

  // gemm1 + W2 transpose overlapped in one dispatch (13-block interleave: 5 gemm1, 8 transpose)
  ffn1_kernel<<<6656, 256, 0, stream>>>(xe, W1T, used, act, W2, W2T);

  gemm2_kernel<<<dim3(H_ / 128, ECAP / 128), 256, 0, stream>>>(act, W2T, used, outb);

  combine_kernel<<<NTOK, 256, 0, stream>>>(outb, slot0, slot1, v0, v1, out);
}

// Round 12
// 221.890 us; speedup vs baseline: 1.0178x; 1.0178x over previous
//
#include <hip/hip_runtime.h>
#include <cstdint>

// ---------------- problem constants ----------------
#define E_    8
#define H_    1024
#define F_    2048          // per-half FFN width (W1 has 2F cols)
#define NTOK  4096
#define CAP   1280          // int(1.25 * (4096*2/8))
#define ECAP  (E_*CAP)      // 10240 buffer rows

typedef unsigned short u16;
typedef __attribute__((ext_vector_type(8))) short bf16x8;   // 8 bf16 = 4 VGPRs
typedef __attribute__((ext_vector_type(4))) float f32x4;
typedef __attribute__((ext_vector_type(4))) unsigned short u16x4;

// ---------------- helpers ----------------
__device__ __forceinline__ u16 f2bf(float f) {      // RNE float->bf16
  union { float f; uint32_t u; } v; v.f = f;
  uint32_t r = v.u + 0x7fffu + ((v.u >> 16) & 1u);
  return (u16)(r >> 16);
}

// async global->LDS, 16B per lane; LDS dest = wave-uniform base + lane*16
__device__ __forceinline__ void gld16(const void* gsrc, void* ldst) {
  auto g = reinterpret_cast<const __attribute__((address_space(1))) uint32_t*>(
      reinterpret_cast<uintptr_t>(gsrc));
  auto l = reinterpret_cast<__attribute__((address_space(3))) uint32_t*>(
      reinterpret_cast<uintptr_t>(ldst));
  __builtin_amdgcn_global_load_lds(g, l, 16, 0, 0);
}

// XOR bank swizzle for [rows][64] bf16 LDS tiles: byte ^= ((row&7)<<4)
__device__ __forceinline__ int swz(int row, int chunk) {
  return row * 64 + ((chunk ^ (row & 7)) * 8);
}

// ---------------- K-A: fused {W1,W2 transpose+cvt (R6-proven body)} + router ----------------
// blocks 0..8191: W1 tiles; 8192..12287: W2 tiles; 12288..13311: router (4 tokens each)
__global__ __launch_bounds__(256) void prep_kernel(const float* __restrict__ W1,
                                                   const float* __restrict__ W2,
                                                   u16* __restrict__ W1T,
                                                   u16* __restrict__ W2T,
                                                   const float* __restrict__ x,
                                                   const float* __restrict__ Wr,
                                                   int* __restrict__ e0o, int* __restrict__ e1o,
                                                   float* __restrict__ v0o, float* __restrict__ v1o,
                                                   float* __restrict__ partial) {
  int b = blockIdx.x;
  if (b < 12288) {
    // ------- transpose + fp32->bf16 (64x64 tile, fp32 LDS [64][65]) -------
    __shared__ float tile[64][65];
    const float* in; u16* outp; int R, C, rt, ct;
    if (b < 8192) {
      int slab = b >> 10, t = b & 1023;
      rt = t >> 6; ct = t & 63;               // 16 x 64 tiles
      R = H_; C = 2 * F_;
      in = W1 + (size_t)slab * R * C;
      outp = W1T + (size_t)slab * R * C;
    } else {
      int bb = b - 8192;
      int slab = bb >> 9, t = bb & 511;
      rt = t >> 4; ct = t & 15;               // 32 x 16 tiles
      R = F_; C = H_;
      in = W2 + (size_t)slab * R * C;
      outp = W2T + (size_t)slab * R * C;
    }
    int r0 = rt * 64, c0 = ct * 64;
    int tx = threadIdx.x & 15, ty = threadIdx.x >> 4;
#pragma unroll
    for (int i = 0; i < 4; i++) {
      int row = ty + 16 * i;
      float4 v = *(const float4*)(in + (size_t)(r0 + row) * C + c0 + tx * 4);
      tile[row][tx * 4 + 0] = v.x;
      tile[row][tx * 4 + 1] = v.y;
      tile[row][tx * 4 + 2] = v.z;
      tile[row][tx * 4 + 3] = v.w;
    }
    __syncthreads();
#pragma unroll
    for (int i = 0; i < 4; i++) {
      int c = ty + 16 * i;
      u16x4 bq;
      bq.x = f2bf(tile[tx * 4 + 0][c]);
      bq.y = f2bf(tile[tx * 4 + 1][c]);
      bq.z = f2bf(tile[tx * 4 + 2][c]);
      bq.w = f2bf(tile[tx * 4 + 3][c]);
      *(u16x4*)(outp + (size_t)(c0 + c) * R + r0 + tx * 4) = bq;
    }
  } else {
    // ------- router: 4 tokens per block (one wave each) -------
    int blk = b - 12288;
    int w = threadIdx.x >> 6, l = threadIdx.x & 63;
    int t = blk * 4 + w;
    const float* xr = x + (size_t)t * H_;
    float acc[8] = {0.f,0.f,0.f,0.f,0.f,0.f,0.f,0.f};
#pragma unroll
    for (int it = 0; it < 16; ++it) {
      int h = it * 64 + l;
      float xv = xr[h];
      const float4* wr = (const float4*)(Wr + h * 8);
      float4 wa = wr[0], wb = wr[1];
      acc[0] += xv * wa.x; acc[1] += xv * wa.y; acc[2] += xv * wa.z; acc[3] += xv * wa.w;
      acc[4] += xv * wb.x; acc[5] += xv * wb.y; acc[6] += xv * wb.z; acc[7] += xv * wb.w;
    }
#pragma unroll
    for (int e = 0; e < 8; ++e)
#pragma unroll
      for (int off = 32; off; off >>= 1)
        acc[e] += __shfl_xor(acc[e], off);

    __shared__ float pg[4][8];
    if (l == 0) {
      float mx = acc[0];
#pragma unroll
      for (int e = 1; e < 8; ++e) mx = fmaxf(mx, acc[e]);
      float g[8], s = 0.f;
#pragma unroll
      for (int e = 0; e < 8; ++e) { g[e] = __expf(acc[e] - mx); s += g[e]; }
      float inv = 1.f / s;
#pragma unroll
      for (int e = 0; e < 8; ++e) g[e] *= inv;
      int b0 = 0; float m0 = g[0];
#pragma unroll
      for (int e = 1; e < 8; ++e) if (g[e] > m0) { m0 = g[e]; b0 = e; }
      int b1 = -1; float m1 = -1.f;
#pragma unroll
      for (int e = 0; e < 8; ++e) if (e != b0 && g[e] > m1) { m1 = g[e]; b1 = e; }
      e0o[t] = b0; e1o[t] = b1; v0o[t] = m0; v1o[t] = m1;
#pragma unroll
      for (int e = 0; e < 8; ++e) pg[w][e] = g[e];
    }
    __syncthreads();
    if (threadIdx.x < 8) {
      int e = threadIdx.x;
      partial[blk * 8 + e] = pg[0][e] + pg[1][e] + pg[2][e] + pg[3][e];
    }
  }
}

// ---------------- K-C: capacity scan (+ per-expert used-row counts) ----------------
__global__ __launch_bounds__(256) void scan_kernel(const int* __restrict__ e0i, const int* __restrict__ e1i,
                                                   const float* __restrict__ partial,
                                                   int* __restrict__ slot0, int* __restrict__ slot1,
                                                   int* __restrict__ used_out,
                                                   float* __restrict__ bl_out) {
  __shared__ int c0[256][8], c1[256][8];
  __shared__ float gs[256][8];
  __shared__ int used0_s[8], tot1_s[8];
  int tid = threadIdx.x;

  int le0[16], le1[16];
  int lc0[8] = {0,0,0,0,0,0,0,0}, lc1[8] = {0,0,0,0,0,0,0,0};
  for (int i = 0; i < 16; ++i) {
    int t = tid * 16 + i;
    le0[i] = e0i[t]; le1[i] = e1i[t];
    lc0[le0[i]]++; lc1[le1[i]]++;
  }
#pragma unroll
  for (int e = 0; e < 8; ++e) { c0[tid][e] = lc0[e]; c1[tid][e] = lc1[e]; }

  float g[8] = {0.f,0.f,0.f,0.f,0.f,0.f,0.f,0.f};
  for (int rr = 0; rr < 4; ++rr)
#pragma unroll
    for (int e = 0; e < 8; ++e) g[e] += partial[(tid + rr * 256) * 8 + e];
#pragma unroll
  for (int e = 0; e < 8; ++e) gs[tid][e] = g[e];
  __syncthreads();

  for (int d = 1; d < 256; d <<= 1) {
    int t0[8], t1[8];
    bool a = (tid >= d);
    if (a) {
#pragma unroll
      for (int e = 0; e < 8; ++e) { t0[e] = c0[tid - d][e]; t1[e] = c1[tid - d][e]; }
    }
    __syncthreads();
    if (a) {
#pragma unroll
      for (int e = 0; e < 8; ++e) { c0[tid][e] += t0[e]; c1[tid][e] += t1[e]; }
    }
    __syncthreads();
  }
  for (int s = 128; s > 0; s >>= 1) {
    if (tid < s)
#pragma unroll
      for (int e = 0; e < 8; ++e) gs[tid][e] += gs[tid + s][e];
    __syncthreads();
  }
  if (tid < 8) {
    int e = tid;
    int u0 = min(c0[255][e], CAP);
    int t1 = c1[255][e];
    used0_s[e] = u0;
    tot1_s[e] = t1;
    used_out[e] = u0 + min(t1, max(0, CAP - u0));
  }
  __syncthreads();

  int ex0[8], ex1[8];
#pragma unroll
  for (int e = 0; e < 8; ++e) { ex0[e] = c0[tid][e] - lc0[e]; ex1[e] = c1[tid][e] - lc1[e]; }
  int r0c[8] = {0,0,0,0,0,0,0,0}, r1c[8] = {0,0,0,0,0,0,0,0};
  for (int i = 0; i < 16; ++i) {
    int t = tid * 16 + i;
    int e = le0[i];
    int pos = ex0[e] + r0c[e]; r0c[e]++;
    slot0[t] = (pos < CAP) ? (e * CAP + pos) : -1;
    e = le1[i];
    pos = ex1[e] + r1c[e] + used0_s[e]; r1c[e]++;
    slot1[t] = (pos < CAP) ? (e * CAP + pos) : -1;
  }

  if (tid == 0) {
    float bl = 0.f;
    for (int e = 0; e < 8; ++e) {
      int u1 = min(tot1_s[e], max(0, CAP - used0_s[e]));
      float used = (float)(used0_s[e] + u1);
      float fu = fmaxf(used, 1e-9f) / (8192.f + 1e-9f);
      bl += (gs[0][e] / (float)NTOK) * fu;
    }
    bl_out[0] = bl * 8.f;
  }
}

// ---------------- K-D: scatter tokens into expert buffer (bf16) ----------------
__global__ __launch_bounds__(256) void scatter_kernel(const float* __restrict__ x,
                                                      const int* __restrict__ slot0,
                                                      const int* __restrict__ slot1,
                                                      u16* __restrict__ xe) {
  int t = blockIdx.x, tid = threadIdx.x;
  float4 vv = *(const float4*)(x + (size_t)t * H_ + tid * 4);
  u16x4 b;
  b.x = f2bf(vv.x); b.y = f2bf(vv.y); b.z = f2bf(vv.z); b.w = f2bf(vv.w);
  int s0 = slot0[t], s1 = slot1[t];
  if (s0 >= 0) *(u16x4*)(xe + (size_t)s0 * H_ + tid * 4) = b;
  if (s1 >= 0) *(u16x4*)(xe + (size_t)s1 * H_ + tid * 4) = b;
}

// ---------------- K-E: GEMM1 + SwiGLU fused (128x64-dual, XOR-swizzled LDS, early-exit) ----------------
__global__ __launch_bounds__(256, 2) void gemm1_kernel(const u16* __restrict__ xe,
                                                       const u16* __restrict__ W1T,
                                                       const int* __restrict__ used_tot,
                                                       u16* __restrict__ act) {
  const int mbase = blockIdx.y * 128;
  const int e = mbase / 1280;
  if (mbase - e * 1280 >= used_tot[e]) return;

  __shared__ u16 As[128 * 64];
  __shared__ u16 Bsa[64 * 64];
  __shared__ u16 Bsb[64 * 64];
  const int tid = threadIdx.x;
  const int w = tid >> 6, l = tid & 63;
  const int wm = w & 1, wn = w >> 1;
  const int nbase = blockIdx.x * 64;
  const u16* Ap = xe + (size_t)mbase * H_;
  const u16* Ba = W1T + (size_t)e * 4096 * H_ + (size_t)nbase * H_;
  const u16* Bb = Ba + (size_t)F_ * H_;
  const int lrow = l >> 3;
  const int lcol = (((l & 7) ^ lrow) * 8);    // pre-swizzled global chunk

  f32x4 acca[4][2] = {};
  f32x4 accb[4][2] = {};

  for (int kt = 0; kt < 16; ++kt) {
    int k0 = kt * 64;
#pragma unroll
    for (int r = 0; r < 4; ++r) {
      int row0 = w * 32 + r * 8;
      gld16(Ap + (size_t)(row0 + lrow) * H_ + k0 + lcol, &As[row0 * 64]);
    }
#pragma unroll
    for (int r = 0; r < 2; ++r) {
      int row0 = w * 16 + r * 8;
      gld16(Ba + (size_t)(row0 + lrow) * H_ + k0 + lcol, &Bsa[row0 * 64]);
      gld16(Bb + (size_t)(row0 + lrow) * H_ + k0 + lcol, &Bsb[row0 * 64]);
    }
    __syncthreads();
#pragma unroll
    for (int kk = 0; kk < 64; kk += 32) {
      const int ck = (kk >> 3) + (l >> 4);
      bf16x8 af[4], ba[2], bb[2];
#pragma unroll
      for (int i = 0; i < 4; ++i)
        af[i] = *(const bf16x8*)&As[swz(wm * 64 + i * 16 + (l & 15), ck)];
#pragma unroll
      for (int j = 0; j < 2; ++j) {
        ba[j] = *(const bf16x8*)&Bsa[swz(wn * 32 + j * 16 + (l & 15), ck)];
        bb[j] = *(const bf16x8*)&Bsb[swz(wn * 32 + j * 16 + (l & 15), ck)];
      }
#pragma unroll
      for (int i = 0; i < 4; ++i)
#pragma unroll
        for (int j = 0; j < 2; ++j) {
          acca[i][j] = __builtin_amdgcn_mfma_f32_16x16x32_bf16(af[i], ba[j], acca[i][j], 0, 0, 0);
          accb[i][j] = __builtin_amdgcn_mfma_f32_16x16x32_bf16(af[i], bb[j], accb[i][j], 0, 0, 0);
        }
    }
    __syncthreads();
  }
#pragma unroll
  for (int i = 0; i < 4; ++i)
#pragma unroll
    for (int j = 0; j < 2; ++j)
#pragma unroll
      for (int r = 0; r < 4; ++r) {
        int m = mbase + wm * 64 + i * 16 + (l >> 4) * 4 + r;
        int f = nbase + wn * 32 + j * 16 + (l & 15);
        float a = acca[i][j][r];
        float b = accb[i][j][r];
        float s = a / (1.f + __expf(-a));
        act[(size_t)m * F_ + f] = f2bf(s * b);
      }
}

// ---------------- K-F: GEMM2 (128x128, XOR-swizzled LDS, early-exit) ----------------
__global__ __launch_bounds__(256, 2) void gemm2_kernel(const u16* __restrict__ act,
                                                       const u16* __restrict__ W2T,
                                                       const int* __restrict__ used_tot,
                                                       float* __restrict__ outb) {
  const int mbase = blockIdx.y * 128;
  const int e = mbase / 1280;
  if (mbase - e * 1280 >= used_tot[e]) return;

  __shared__ u16 As[128 * 64];
  __shared__ u16 Bs[128 * 64];
  const int tid = threadIdx.x;
  const int w = tid >> 6, l = tid & 63;
  const int wm = w & 1, wn = w >> 1;
  const int nbase = blockIdx.x * 128;
  const u16* Ap = act + (size_t)mbase * F_;
  const u16* Bp = W2T + (size_t)e * H_ * F_ + (size_t)nbase * F_;
  const int lrow = l >> 3;
  const int lcol = (((l & 7) ^ lrow) * 8);

  f32x4 acc[4][4] = {};

  for (int kt = 0; kt < 32; ++kt) {
    int k0 = kt * 64;
#pragma unroll
    for (int r = 0; r < 4; ++r) {
      int row0 = w * 32 + r * 8;
      gld16(Ap + (size_t)(row0 + lrow) * F_ + k0 + lcol, &As[row0 * 64]);
      gld16(Bp + (size_t)(row0 + lrow) * F_ + k0 + lcol, &Bs[row0 * 64]);
    }
    __syncthreads();
#pragma unroll
    for (int kk = 0; kk < 64; kk += 32) {
      const int ck = (kk >> 3) + (l >> 4);
      bf16x8 af[4], bf[4];
#pragma unroll
      for (int i = 0; i < 4; ++i)
        af[i] = *(const bf16x8*)&As[swz(wm * 64 + i * 16 + (l & 15), ck)];
#pragma unroll
      for (int j = 0; j < 4; ++j)
        bf[j] = *(const bf16x8*)&Bs[swz(wn * 64 + j * 16 + (l & 15), ck)];
#pragma unroll
      for (int i = 0; i < 4; ++i)
#pragma unroll
        for (int j = 0; j < 4; ++j)
          acc[i][j] = __builtin_amdgcn_mfma_f32_16x16x32_bf16(af[i], bf[j], acc[i][j], 0, 0, 0);
    }
    __syncthreads();
  }
#pragma unroll
  for (int i = 0; i < 4; ++i)
#pragma unroll
    for (int j = 0; j < 4; ++j)
#pragma unroll
      for (int r = 0; r < 4; ++r) {
        int m = mbase + wm * 64 + i * 16 + (l >> 4) * 4 + r;
        int n = nbase + wn * 64 + j * 16 + (l & 15);
        outb[(size_t)m * H_ + n] = acc[i][j][r];
      }
}

// ---------------- K-G: gather + weighted combine ----------------
__global__ __launch_bounds__(256) void combine_kernel(const float* __restrict__ outb,
                                                      const int* __restrict__ slot0,
                                                      const int* __restrict__ slot1,
                                                      const float* __restrict__ v0,
                                                      const float* __restrict__ v1,
                                                      float* __restrict__ y) {
  int t = blockIdx.x, tid = threadIdx.x;
  int s0 = slot0[t], s1 = slot1[t];
  float w0 = v0[t], w1 = v1[t];
  float4 r; r.x = 0.f; r.y = 0.f; r.z = 0.f; r.w = 0.f;
  if (s0 >= 0) {
    float4 a = *(const float4*)(outb + (size_t)s0 * H_ + tid * 4);
    r.x += w0 * a.x; r.y += w0 * a.y; r.z += w0 * a.z; r.w += w0 * a.w;
  }
  if (s1 >= 0) {
    float4 a = *(const float4*)(outb + (size_t)s1 * H_ + tid * 4);
    r.x += w1 * a.x; r.y += w1 * a.y; r.z += w1 * a.z; r.w += w1 * a.w;
  }
  *(float4*)(y + (size_t)t * H_ + tid * 4) = r;
}

// ---------------- workspace layout (bytes) ----------------
#define OFF_W1T   ((size_t)0)           // 8*4096*1024*2  = 64 MiB
#define OFF_W2T   ((size_t)67108864)    // 8*1024*2048*2  = 32 MiB
#define OFF_XE    ((size_t)100663296)   // 10240*1024*2   = 20 MiB
#define OFF_ACT   ((size_t)121634816)   // 10240*2048*2   = 40 MiB
#define OFF_OUTB  ((size_t)163577856)   // 10240*1024*4   = 40 MiB
#define OFF_SLOT0 ((size_t)205520896)
#define OFF_SLOT1 ((size_t)205537280)
#define OFF_V0    ((size_t)205553664)
#define OFF_V1    ((size_t)205570048)
#define OFF_E0    ((size_t)205586432)
#define OFF_E1    ((size_t)205602816)
#define OFF_PART  ((size_t)205619200)   // 1024*8*4
#define OFF_USED  ((size_t)205651968)   // 8*4

extern "C" void kernel_launch(void* const* d_in, const int* in_sizes, int n_in,
                              void* d_out, int out_size, void* d_ws, size_t ws_size,
                              hipStream_t stream) {
  const float* x  = (const float*)d_in[0];
  const float* Wr = (const float*)d_in[1];
  const float* W1 = (const float*)d_in[2];
  const float* W2 = (const float*)d_in[3];
  float* out = (float*)d_out;

  uint8_t* ws = (uint8_t*)d_ws;
  u16*   W1T   = (u16*)(ws + OFF_W1T);
  u16*   W2T   = (u16*)(ws + OFF_W2T);
  u16*   xe    = (u16*)(ws + OFF_XE);
  u16*   act   = (u16*)(ws + OFF_ACT);
  float* outb  = (float*)(ws + OFF_OUTB);
  int*   slot0 = (int*)(ws + OFF_SLOT0);
  int*   slot1 = (int*)(ws + OFF_SLOT1);
  float* v0    = (float*)(ws + OFF_V0);
  float* v1    = (float*)(ws + OFF_V1);
  int*   e0    = (int*)(ws + OFF_E0);
  int*   e1    = (int*)(ws + OFF_E1);
  float* part  = (float*)(ws + OFF_PART);
  int*   used  = (int*)(ws + OFF_USED);

  // fused: weight transpose/convert (R6 body) + router
  prep_kernel<<<13312, 256, 0, stream>>>(W1, W2, W1T, W2T, x, Wr, e0, e1, v0, v1, part);

  scan_kernel<<<1, 256, 0, stream>>>(e0, e1, part, slot0, slot1, used, out + (size_t)NTOK * H_);
  scatter_kernel<<<NTOK, 256, 0, stream>>>(x, slot0, slot1, xe);

  // expert FFN (blocks beyond used rows exit immediately)
  gemm1_kernel<<<dim3(F_ / 64, ECAP / 128), 256, 0, stream>>>(xe, W1T, used, act);
  gemm2_kernel<<<dim3(H_ / 128, ECAP / 128), 256, 0, stream>>>(act, W2T, used, outb);

  // combine
  combine_kernel<<<NTOK, 256, 0, stream>>>(outb, slot0, slot1, v0, v1, out);
}

// Round 13
// 220.578 us; speedup vs baseline: 1.0239x; 1.0059x over previous
//
#include <hip/hip_runtime.h>
#include <cstdint>

// ---------------- problem constants ----------------
#define E_    8
#define H_    1024
#define F_    2048          // per-half FFN width (W1 has 2F cols)
#define NTOK  4096
#define CAP   1280          // int(1.25 * (4096*2/8))
#define ECAP  (E_*CAP)      // 10240 buffer rows

typedef unsigned short u16;
typedef __attribute__((ext_vector_type(8))) short bf16x8;   // 8 bf16 = 4 VGPRs
typedef __attribute__((ext_vector_type(4))) float f32x4;
typedef __attribute__((ext_vector_type(4))) unsigned short u16x4;

// ---------------- helpers ----------------
__device__ __forceinline__ u16 f2bf(float f) {      // RNE float->bf16
  union { float f; uint32_t u; } v; v.f = f;
  uint32_t r = v.u + 0x7fffu + ((v.u >> 16) & 1u);
  return (u16)(r >> 16);
}

// async global->LDS, 16B per lane; LDS dest = wave-uniform base + lane*16
__device__ __forceinline__ void gld16(const void* gsrc, void* ldst) {
  auto g = reinterpret_cast<const __attribute__((address_space(1))) uint32_t*>(
      reinterpret_cast<uintptr_t>(gsrc));
  auto l = reinterpret_cast<__attribute__((address_space(3))) uint32_t*>(
      reinterpret_cast<uintptr_t>(ldst));
  __builtin_amdgcn_global_load_lds(g, l, 16, 0, 0);
}

// XOR bank swizzle for [rows][64] bf16 LDS tiles: byte ^= ((row&7)<<4)
__device__ __forceinline__ int swz(int row, int chunk) {
  return row * 64 + ((chunk ^ (row & 7)) * 8);
}

// ---------------- K-A: fused {router FIRST} + {W1,W2 transpose+cvt} ----------------
// blocks 0..1023: router (dispatched first -> overlaps transpose stream);
// blocks 1024..9215: W1 tiles; 9216..13311: W2 tiles.
__global__ __launch_bounds__(256) void prep_kernel(const float* __restrict__ W1,
                                                   const float* __restrict__ W2,
                                                   u16* __restrict__ W1T,
                                                   u16* __restrict__ W2T,
                                                   const float* __restrict__ x,
                                                   const float* __restrict__ Wr,
                                                   int* __restrict__ e0o, int* __restrict__ e1o,
                                                   float* __restrict__ v0o, float* __restrict__ v1o,
                                                   float* __restrict__ partial) {
  int b = blockIdx.x;
  if (b >= 1024) {
    // ------- transpose + fp32->bf16 (64x64 tile, fp32 LDS [64][65]) -------
    int tt = b - 1024;
    __shared__ float tile[64][65];
    const float* in; u16* outp; int R, C, rt, ct;
    if (tt < 8192) {
      int slab = tt >> 10, t = tt & 1023;
      rt = t >> 6; ct = t & 63;               // 16 x 64 tiles
      R = H_; C = 2 * F_;
      in = W1 + (size_t)slab * R * C;
      outp = W1T + (size_t)slab * R * C;
    } else {
      int bb = tt - 8192;
      int slab = bb >> 9, t = bb & 511;
      rt = t >> 4; ct = t & 15;               // 32 x 16 tiles
      R = F_; C = H_;
      in = W2 + (size_t)slab * R * C;
      outp = W2T + (size_t)slab * R * C;
    }
    int r0 = rt * 64, c0 = ct * 64;
    int tx = threadIdx.x & 15, ty = threadIdx.x >> 4;
#pragma unroll
    for (int i = 0; i < 4; i++) {
      int row = ty + 16 * i;
      float4 v = *(const float4*)(in + (size_t)(r0 + row) * C + c0 + tx * 4);
      tile[row][tx * 4 + 0] = v.x;
      tile[row][tx * 4 + 1] = v.y;
      tile[row][tx * 4 + 2] = v.z;
      tile[row][tx * 4 + 3] = v.w;
    }
    __syncthreads();
#pragma unroll
    for (int i = 0; i < 4; i++) {
      int c = ty + 16 * i;
      u16x4 bq;
      bq.x = f2bf(tile[tx * 4 + 0][c]);
      bq.y = f2bf(tile[tx * 4 + 1][c]);
      bq.z = f2bf(tile[tx * 4 + 2][c]);
      bq.w = f2bf(tile[tx * 4 + 3][c]);
      *(u16x4*)(outp + (size_t)(c0 + c) * R + r0 + tx * 4) = bq;
    }
  } else {
    // ------- router: 4 tokens per block (one wave each) -------
    int blk = b;
    int w = threadIdx.x >> 6, l = threadIdx.x & 63;
    int t = blk * 4 + w;
    const float* xr = x + (size_t)t * H_;
    float acc[8] = {0.f,0.f,0.f,0.f,0.f,0.f,0.f,0.f};
#pragma unroll
    for (int it = 0; it < 16; ++it) {
      int h = it * 64 + l;
      float xv = xr[h];
      const float4* wr = (const float4*)(Wr + h * 8);
      float4 wa = wr[0], wb = wr[1];
      acc[0] += xv * wa.x; acc[1] += xv * wa.y; acc[2] += xv * wa.z; acc[3] += xv * wa.w;
      acc[4] += xv * wb.x; acc[5] += xv * wb.y; acc[6] += xv * wb.z; acc[7] += xv * wb.w;
    }
#pragma unroll
    for (int e = 0; e < 8; ++e)
#pragma unroll
      for (int off = 32; off; off >>= 1)
        acc[e] += __shfl_xor(acc[e], off);

    __shared__ float pg[4][8];
    if (l == 0) {
      float mx = acc[0];
#pragma unroll
      for (int e = 1; e < 8; ++e) mx = fmaxf(mx, acc[e]);
      float g[8], s = 0.f;
#pragma unroll
      for (int e = 0; e < 8; ++e) { g[e] = __expf(acc[e] - mx); s += g[e]; }
      float inv = 1.f / s;
#pragma unroll
      for (int e = 0; e < 8; ++e) g[e] *= inv;
      int b0 = 0; float m0 = g[0];
#pragma unroll
      for (int e = 1; e < 8; ++e) if (g[e] > m0) { m0 = g[e]; b0 = e; }
      int b1 = -1; float m1 = -1.f;
#pragma unroll
      for (int e = 0; e < 8; ++e) if (e != b0 && g[e] > m1) { m1 = g[e]; b1 = e; }
      e0o[t] = b0; e1o[t] = b1; v0o[t] = m0; v1o[t] = m1;
#pragma unroll
      for (int e = 0; e < 8; ++e) pg[w][e] = g[e];
    }
    __syncthreads();
    if (threadIdx.x < 8) {
      int e = threadIdx.x;
      partial[blk * 8 + e] = pg[0][e] + pg[1][e] + pg[2][e] + pg[3][e];
    }
  }
}

// ---------------- K-C: capacity scan (+ per-expert used-row counts) ----------------
__global__ __launch_bounds__(256) void scan_kernel(const int* __restrict__ e0i, const int* __restrict__ e1i,
                                                   const float* __restrict__ partial,
                                                   int* __restrict__ slot0, int* __restrict__ slot1,
                                                   int* __restrict__ used_out,
                                                   float* __restrict__ bl_out) {
  __shared__ int c0[256][8], c1[256][8];
  __shared__ float gs[256][8];
  __shared__ int used0_s[8], tot1_s[8];
  int tid = threadIdx.x;

  int le0[16], le1[16];
  int lc0[8] = {0,0,0,0,0,0,0,0}, lc1[8] = {0,0,0,0,0,0,0,0};
  for (int i = 0; i < 16; ++i) {
    int t = tid * 16 + i;
    le0[i] = e0i[t]; le1[i] = e1i[t];
    lc0[le0[i]]++; lc1[le1[i]]++;
  }
#pragma unroll
  for (int e = 0; e < 8; ++e) { c0[tid][e] = lc0[e]; c1[tid][e] = lc1[e]; }

  float g[8] = {0.f,0.f,0.f,0.f,0.f,0.f,0.f,0.f};
  for (int rr = 0; rr < 4; ++rr)
#pragma unroll
    for (int e = 0; e < 8; ++e) g[e] += partial[(tid + rr * 256) * 8 + e];
#pragma unroll
  for (int e = 0; e < 8; ++e) gs[tid][e] = g[e];
  __syncthreads();

  for (int d = 1; d < 256; d <<= 1) {
    int t0[8], t1[8];
    bool a = (tid >= d);
    if (a) {
#pragma unroll
      for (int e = 0; e < 8; ++e) { t0[e] = c0[tid - d][e]; t1[e] = c1[tid - d][e]; }
    }
    __syncthreads();
    if (a) {
#pragma unroll
      for (int e = 0; e < 8; ++e) { c0[tid][e] += t0[e]; c1[tid][e] += t1[e]; }
    }
    __syncthreads();
  }
  for (int s = 128; s > 0; s >>= 1) {
    if (tid < s)
#pragma unroll
      for (int e = 0; e < 8; ++e) gs[tid][e] += gs[tid + s][e];
    __syncthreads();
  }
  if (tid < 8) {
    int e = tid;
    int u0 = min(c0[255][e], CAP);
    int t1 = c1[255][e];
    used0_s[e] = u0;
    tot1_s[e] = t1;
    used_out[e] = u0 + min(t1, max(0, CAP - u0));
  }
  __syncthreads();

  int ex0[8], ex1[8];
#pragma unroll
  for (int e = 0; e < 8; ++e) { ex0[e] = c0[tid][e] - lc0[e]; ex1[e] = c1[tid][e] - lc1[e]; }
  int r0c[8] = {0,0,0,0,0,0,0,0}, r1c[8] = {0,0,0,0,0,0,0,0};
  for (int i = 0; i < 16; ++i) {
    int t = tid * 16 + i;
    int e = le0[i];
    int pos = ex0[e] + r0c[e]; r0c[e]++;
    slot0[t] = (pos < CAP) ? (e * CAP + pos) : -1;
    e = le1[i];
    pos = ex1[e] + r1c[e] + used0_s[e]; r1c[e]++;
    slot1[t] = (pos < CAP) ? (e * CAP + pos) : -1;
  }

  if (tid == 0) {
    float bl = 0.f;
    for (int e = 0; e < 8; ++e) {
      int u1 = min(tot1_s[e], max(0, CAP - used0_s[e]));
      float used = (float)(used0_s[e] + u1);
      float fu = fmaxf(used, 1e-9f) / (8192.f + 1e-9f);
      bl += (gs[0][e] / (float)NTOK) * fu;
    }
    bl_out[0] = bl * 8.f;
  }
}

// ---------------- K-D: scatter tokens into expert buffer (bf16) ----------------
__global__ __launch_bounds__(256) void scatter_kernel(const float* __restrict__ x,
                                                      const int* __restrict__ slot0,
                                                      const int* __restrict__ slot1,
                                                      u16* __restrict__ xe) {
  int t = blockIdx.x, tid = threadIdx.x;
  float4 vv = *(const float4*)(x + (size_t)t * H_ + tid * 4);
  u16x4 b;
  b.x = f2bf(vv.x); b.y = f2bf(vv.y); b.z = f2bf(vv.z); b.w = f2bf(vv.w);
  int s0 = slot0[t], s1 = slot1[t];
  if (s0 >= 0) *(u16x4*)(xe + (size_t)s0 * H_ + tid * 4) = b;
  if (s1 >= 0) *(u16x4*)(xe + (size_t)s1 * H_ + tid * 4) = b;
}

// ---------------- K-E: GEMM1 + SwiGLU fused (128x64-dual, XOR-swizzled LDS, early-exit) ----------------
__global__ __launch_bounds__(256, 2) void gemm1_kernel(const u16* __restrict__ xe,
                                                       const u16* __restrict__ W1T,
                                                       const int* __restrict__ used_tot,
                                                       u16* __restrict__ act) {
  const int mbase = blockIdx.y * 128;
  const int e = mbase / 1280;
  if (mbase - e * 1280 >= used_tot[e]) return;

  __shared__ u16 As[128 * 64];
  __shared__ u16 Bsa[64 * 64];
  __shared__ u16 Bsb[64 * 64];
  const int tid = threadIdx.x;
  const int w = tid >> 6, l = tid & 63;
  const int wm = w & 1, wn = w >> 1;
  const int nbase = blockIdx.x * 64;
  const u16* Ap = xe + (size_t)mbase * H_;
  const u16* Ba = W1T + (size_t)e * 4096 * H_ + (size_t)nbase * H_;
  const u16* Bb = Ba + (size_t)F_ * H_;
  const int lrow = l >> 3;
  const int lcol = (((l & 7) ^ lrow) * 8);    // pre-swizzled global chunk

  f32x4 acca[4][2] = {};
  f32x4 accb[4][2] = {};

  for (int kt = 0; kt < 16; ++kt) {
    int k0 = kt * 64;
#pragma unroll
    for (int r = 0; r < 4; ++r) {
      int row0 = w * 32 + r * 8;
      gld16(Ap + (size_t)(row0 + lrow) * H_ + k0 + lcol, &As[row0 * 64]);
    }
#pragma unroll
    for (int r = 0; r < 2; ++r) {
      int row0 = w * 16 + r * 8;
      gld16(Ba + (size_t)(row0 + lrow) * H_ + k0 + lcol, &Bsa[row0 * 64]);
      gld16(Bb + (size_t)(row0 + lrow) * H_ + k0 + lcol, &Bsb[row0 * 64]);
    }
    __syncthreads();
#pragma unroll
    for (int kk = 0; kk < 64; kk += 32) {
      const int ck = (kk >> 3) + (l >> 4);
      bf16x8 af[4], ba[2], bb[2];
#pragma unroll
      for (int i = 0; i < 4; ++i)
        af[i] = *(const bf16x8*)&As[swz(wm * 64 + i * 16 + (l & 15), ck)];
#pragma unroll
      for (int j = 0; j < 2; ++j) {
        ba[j] = *(const bf16x8*)&Bsa[swz(wn * 32 + j * 16 + (l & 15), ck)];
        bb[j] = *(const bf16x8*)&Bsb[swz(wn * 32 + j * 16 + (l & 15), ck)];
      }
#pragma unroll
      for (int i = 0; i < 4; ++i)
#pragma unroll
        for (int j = 0; j < 2; ++j) {
          acca[i][j] = __builtin_amdgcn_mfma_f32_16x16x32_bf16(af[i], ba[j], acca[i][j], 0, 0, 0);
          accb[i][j] = __builtin_amdgcn_mfma_f32_16x16x32_bf16(af[i], bb[j], accb[i][j], 0, 0, 0);
        }
    }
    __syncthreads();
  }
#pragma unroll
  for (int i = 0; i < 4; ++i)
#pragma unroll
    for (int j = 0; j < 2; ++j)
#pragma unroll
      for (int r = 0; r < 4; ++r) {
        int m = mbase + wm * 64 + i * 16 + (l >> 4) * 4 + r;
        int f = nbase + wn * 32 + j * 16 + (l & 15);
        float a = acca[i][j][r];
        float b = accb[i][j][r];
        float s = a / (1.f + __expf(-a));
        act[(size_t)m * F_ + f] = f2bf(s * b);
      }
}

// ---------------- K-F: GEMM2 (128x128, XOR-swizzled LDS, early-exit) ----------------
__global__ __launch_bounds__(256, 2) void gemm2_kernel(const u16* __restrict__ act,
                                                       const u16* __restrict__ W2T,
                                                       const int* __restrict__ used_tot,
                                                       float* __restrict__ outb) {
  const int mbase = blockIdx.y * 128;
  const int e = mbase / 1280;
  if (mbase - e * 1280 >= used_tot[e]) return;

  __shared__ u16 As[128 * 64];
  __shared__ u16 Bs[128 * 64];
  const int tid = threadIdx.x;
  const int w = tid >> 6, l = tid & 63;
  const int wm = w & 1, wn = w >> 1;
  const int nbase = blockIdx.x * 128;
  const u16* Ap = act + (size_t)mbase * F_;
  const u16* Bp = W2T + (size_t)e * H_ * F_ + (size_t)nbase * F_;
  const int lrow = l >> 3;
  const int lcol = (((l & 7) ^ lrow) * 8);

  f32x4 acc[4][4] = {};

  for (int kt = 0; kt < 32; ++kt) {
    int k0 = kt * 64;
#pragma unroll
    for (int r = 0; r < 4; ++r) {
      int row0 = w * 32 + r * 8;
      gld16(Ap + (size_t)(row0 + lrow) * F_ + k0 + lcol, &As[row0 * 64]);
      gld16(Bp + (size_t)(row0 + lrow) * F_ + k0 + lcol, &Bs[row0 * 64]);
    }
    __syncthreads();
#pragma unroll
    for (int kk = 0; kk < 64; kk += 32) {
      const int ck = (kk >> 3) + (l >> 4);
      bf16x8 af[4], bf[4];
#pragma unroll
      for (int i = 0; i < 4; ++i)
        af[i] = *(const bf16x8*)&As[swz(wm * 64 + i * 16 + (l & 15), ck)];
#pragma unroll
      for (int j = 0; j < 4; ++j)
        bf[j] = *(const bf16x8*)&Bs[swz(wn * 64 + j * 16 + (l & 15), ck)];
#pragma unroll
      for (int i = 0; i < 4; ++i)
#pragma unroll
        for (int j = 0; j < 4; ++j)
          acc[i][j] = __builtin_amdgcn_mfma_f32_16x16x32_bf16(af[i], bf[j], acc[i][j], 0, 0, 0);
    }
    __syncthreads();
  }
#pragma unroll
  for (int i = 0; i < 4; ++i)
#pragma unroll
    for (int j = 0; j < 4; ++j)
#pragma unroll
      for (int r = 0; r < 4; ++r) {
        int m = mbase + wm * 64 + i * 16 + (l >> 4) * 4 + r;
        int n = nbase + wn * 64 + j * 16 + (l & 15);
        outb[(size_t)m * H_ + n] = acc[i][j][r];
      }
}

// ---------------- K-G: gather + weighted combine ----------------
__global__ __launch_bounds__(256) void combine_kernel(const float* __restrict__ outb,
                                                      const int* __restrict__ slot0,
                                                      const int* __restrict__ slot1,
                                                      const float* __restrict__ v0,
                                                      const float* __restrict__ v1,
                                                      float* __restrict__ y) {
  int t = blockIdx.x, tid = threadIdx.x;
  int s0 = slot0[t], s1 = slot1[t];
  float w0 = v0[t], w1 = v1[t];
  float4 r; r.x = 0.f; r.y = 0.f; r.z = 0.f; r.w = 0.f;
  if (s0 >= 0) {
    float4 a = *(const float4*)(outb + (size_t)s0 * H_ + tid * 4);
    r.x += w0 * a.x; r.y += w0 * a.y; r.z += w0 * a.z; r.w += w0 * a.w;
  }
  if (s1 >= 0) {
    float4 a = *(const float4*)(outb + (size_t)s1 * H_ + tid * 4);
    r.x += w1 * a.x; r.y += w1 * a.y; r.z += w1 * a.z; r.w += w1 * a.w;
  }
  *(float4*)(y + (size_t)t * H_ + tid * 4) = r;
}

// ---------------- workspace layout (bytes) ----------------
#define OFF_W1T   ((size_t)0)           // 8*4096*1024*2  = 64 MiB
#define OFF_W2T   ((size_t)67108864)    // 8*1024*2048*2  = 32 MiB
#define OFF_XE    ((size_t)100663296)   // 10240*1024*2   = 20 MiB
#define OFF_ACT   ((size_t)121634816)   // 10240*2048*2   = 40 MiB
#define OFF_OUTB  ((size_t)163577856)   // 10240*1024*4   = 40 MiB
#define OFF_SLOT0 ((size_t)205520896)
#define OFF_SLOT1 ((size_t)205537280)
#define OFF_V0    ((size_t)205553664)
#define OFF_V1    ((size_t)205570048)
#define OFF_E0    ((size_t)205586432)
#define OFF_E1    ((size_t)205602816)
#define OFF_PART  ((size_t)205619200)   // 1024*8*4
#define OFF_USED  ((size_t)205651968)   // 8*4

extern "C" void kernel_launch(void* const* d_in, const int* in_sizes, int n_in,
                              void* d_out, int out_size, void* d_ws, size_t ws_size,
                              hipStream_t stream) {
  const float* x  = (const float*)d_in[0];
  const float* Wr = (const float*)d_in[1];
  const float* W1 = (const float*)d_in[2];
  const float* W2 = (const float*)d_in[3];
  float* out = (float*)d_out;

  uint8_t* ws = (uint8_t*)d_ws;
  u16*   W1T   = (u16*)(ws + OFF_W1T);
  u16*   W2T   = (u16*)(ws + OFF_W2T);
  u16*   xe    = (u16*)(ws + OFF_XE);
  u16*   act   = (u16*)(ws + OFF_ACT);
  float* outb  = (float*)(ws + OFF_OUTB);
  int*   slot0 = (int*)(ws + OFF_SLOT0);
  int*   slot1 = (int*)(ws + OFF_SLOT1);
  float* v0    = (float*)(ws + OFF_V0);
  float* v1    = (float*)(ws + OFF_V1);
  int*   e0    = (int*)(ws + OFF_E0);
  int*   e1    = (int*)(ws + OFF_E1);
  float* part  = (float*)(ws + OFF_PART);
  int*   used  = (int*)(ws + OFF_USED);

  // fused: router (blocks 0..1023, dispatched first) + weight transpose/convert
  prep_kernel<<<13312, 256, 0, stream>>>(W1, W2, W1T, W2T, x, Wr, e0, e1, v0, v1, part);

  scan_kernel<<<1, 256, 0, stream>>>(e0, e1, part, slot0, slot1, used, out + (size_t)NTOK * H_);
  scatter_kernel<<<NTOK, 256, 0, stream>>>(x, slot0, slot1, xe);

  // expert FFN (blocks beyond used rows exit immediately)
  gemm1_kernel<<<dim3(F_ / 64, ECAP / 128), 256, 0, stream>>>(xe, W1T, used, act);
  gemm2_kernel<<<dim3(H_ / 128, ECAP / 128), 256, 0, stream>>>(act, W2T, used, outb);

  // combine
  combine_kernel<<<NTOK, 256, 0, stream>>>(outb, slot0, slot1, v0, v1, out);
}